// Round 1
// baseline (84.498 us; speedup 1.0000x reference)
//
#include <hip/hip_runtime.h>

// DeLaN forward, D=2, H1=64. One thread per sample, fp32 VALU.
// Per-sample state lives in VGPRs; all weight reads are wave-uniform -> SMEM.

__global__ __launch_bounds__(256) void delan_fwd(
    const float* __restrict__ x,
    const float* __restrict__ W1,  const float* __restrict__ b1,
    const float* __restrict__ W1a, const float* __restrict__ b1a,
    const float* __restrict__ W2,  const float* __restrict__ b2,
    const float* __restrict__ W3,  const float* __restrict__ b3,
    const float* __restrict__ W4,  const float* __restrict__ b4,
    float* __restrict__ out, int n_total)
{
    const int n = blockIdx.x * blockDim.x + threadIdx.x;
    if (n >= n_total) return;

    // x = [q0,q1, qd0,qd1, qdd0,qdd1]
    const float x0 = x[6*n+0], x1 = x[6*n+1];
    const float x2 = x[6*n+2], x3 = x[6*n+3];
    const float x4 = x[6*n+4], x5 = x[6*n+5];

    // ---- Layer 1: h1 = leaky_relu(W1 q + b1), u_d[k] = dR1[k]*W1[k,d] ----
    // NOTE: reference uses NEG_SLOPE = -0.01 for the DERIVATIVE (dR1/dR2),
    // while the activation slope is +0.01.
    float h1[64], u0[64], u1[64];
#pragma unroll
    for (int k = 0; k < 64; ++k) {
        const float w0 = W1[2*k], w1 = W1[2*k+1];
        const float pre = fmaf(w0, x0, fmaf(w1, x1, b1[k]));
        const bool pos = pre > 0.0f;
        h1[k] = pos ? pre : 0.01f * pre;
        const float dr = pos ? 1.0f : -0.01f;
        u0[k] = dr * w0;
        u1[k] = dr * w1;
    }

    // ---- Layer 2 + fused second stage ----
    // h2pre[h] = b1a[h] + sum_k W1a[h,k]*h1[k]
    // z_d[h]   =          sum_k W1a[h,k]*u_d[k]
    // then accumulate g, ldpre, lo, and W3/W4 dotted with dh2_dq.
    float g0 = b2[0], g1 = b2[1];
    float l0 = b3[0], l1 = b3[1];   // ldpre accumulators
    float oo = b4[0];               // lo accumulator
    float p00 = 0.f, p01 = 0.f, p10 = 0.f, p11 = 0.f; // W3 . dh2_dq
    float r0  = 0.f, r1  = 0.f;                       // W4 . dh2_dq

#pragma unroll 2
    for (int h = 0; h < 64; ++h) {
        float ah = b1a[h], z0 = 0.f, z1 = 0.f;
        const float* __restrict__ wrow = W1a + h * 64;
#pragma unroll
        for (int k = 0; k < 64; ++k) {
            const float w = wrow[k];        // wave-uniform -> SGPR
            ah = fmaf(w, h1[k], ah);
            z0 = fmaf(w, u0[k], z0);
            z1 = fmaf(w, u1[k], z1);
        }
        const bool pos = ah > 0.0f;
        const float h2 = pos ? ah : 0.01f * ah;
        const float dr = pos ? 1.0f : -0.01f;
        const float d0 = dr * z0, d1 = dr * z1;

        const float w20 = W2[h], w21 = W2[64 + h];
        const float w30 = W3[h], w31 = W3[64 + h];
        const float w4h = W4[h];
        g0  = fmaf(w20, h2, g0);   g1  = fmaf(w21, h2, g1);
        l0  = fmaf(w30, h2, l0);   l1  = fmaf(w31, h2, l1);
        oo  = fmaf(w4h, h2, oo);
        p00 = fmaf(w30, d0, p00);  p01 = fmaf(w30, d1, p01);
        p10 = fmaf(w31, d0, p10);  p11 = fmaf(w31, d1, p11);
        r0  = fmaf(w4h, d0, r0);   r1  = fmaf(w4h, d1, r1);
    }

    // ---- Tail: 2x2 algebra ----
    const float ld0 = fmaxf(l0, 0.0f);
    const float ld1 = fmaxf(l1, 0.0f);
    const float dr30 = (l0 > 0.0f) ? 1.0f : 0.0f;
    const float dr31 = (l1 > 0.0f) ? 1.0f : 0.0f;

    // dld_dq[o][d]
    const float da00 = dr30 * p00, da01 = dr30 * p01;
    const float da10 = dr31 * p10, da11 = dr31 * p11;
    // dlo_dq[d] = r0, r1

    // L = [[l00,0],[l10,l11]]
    const float l00 = ld0, l10 = oo, l11 = ld1;

    // dL_dt entries
    const float m00 = da00 * x2 + da01 * x3;   // dld_dt[0]
    const float m11 = da10 * x2 + da11 * x3;   // dld_dt[1]
    const float m10 = r0  * x2 + r1  * x3;     // dlo_dt

    const float eps = 1e-5f;
    const float Hm00 = fmaf(l00, l00, eps);
    const float Hm01 = l00 * l10;
    const float Hm11 = fmaf(l10, l10, fmaf(l11, l11, eps));

    // dH_dt = L dLt^T + dLt L^T (symmetric)
    const float dH00 = 2.0f * l00 * m00;
    const float dH01 = fmaf(l00, m10, l10 * m00);
    const float dH11 = 2.0f * fmaf(l10, m10, l11 * m11);

    // quad_k = qd^T (dL/dq_k L^T + L dL/dq_k^T) qd
    const float x22 = x2 * x2, x23 = x2 * x3, x33 = x3 * x3;
    // k = 0: a=da00, b=r0, c=da10
    const float quad0 = 2.0f * (da00 * l00 * x22
                      + (fmaf(da00, l10, r0 * l00)) * x23
                      + (fmaf(r0, l10, da10 * l11)) * x33);
    // k = 1: a=da01, b=r1, c=da11
    const float quad1 = 2.0f * (da01 * l00 * x22
                      + (fmaf(da01, l10, r1 * l00)) * x23
                      + (fmaf(r1, l10, da11 * l11)) * x33);

    const float c0 = fmaf(dH00, x2, dH01 * x3) - 0.5f * quad0;
    const float c1 = fmaf(dH01, x2, dH11 * x3) - 0.5f * quad1;

    const float tau0 = fmaf(Hm00, x4, Hm01 * x5) + c0 + g0;
    const float tau1 = fmaf(Hm01, x4, Hm11 * x5) + c1 + g1;

    // ---- Outputs: [tau (N,2) | Hm (N,2,2) | c (N,2) | g (N,2)] ----
    const long long N = n_total;
    float2* tau_out = (float2*)(out) + n;
    float4* hm_out  = (float4*)(out + 2 * N) + n;
    float2* c_out   = (float2*)(out + 6 * N) + n;
    float2* g_out   = (float2*)(out + 8 * N) + n;
    *tau_out = make_float2(tau0, tau1);
    *hm_out  = make_float4(Hm00, Hm01, Hm01, Hm11);
    *c_out   = make_float2(c0, c1);
    *g_out   = make_float2(g0, g1);
}

extern "C" void kernel_launch(void* const* d_in, const int* in_sizes, int n_in,
                              void* d_out, int out_size, void* d_ws, size_t ws_size,
                              hipStream_t stream) {
    const float* x   = (const float*)d_in[0];
    const float* W1  = (const float*)d_in[1];
    const float* b1  = (const float*)d_in[2];
    const float* W1a = (const float*)d_in[3];
    const float* b1a = (const float*)d_in[4];
    const float* W2  = (const float*)d_in[5];
    const float* b2  = (const float*)d_in[6];
    const float* W3  = (const float*)d_in[7];
    const float* b3  = (const float*)d_in[8];
    const float* W4  = (const float*)d_in[9];
    const float* b4  = (const float*)d_in[10];
    float* out = (float*)d_out;

    const int n_total = in_sizes[0] / 6;
    const int block = 256;
    const int grid = (n_total + block - 1) / block;
    delan_fwd<<<grid, block, 0, stream>>>(x, W1, b1, W1a, b1a, W2, b2,
                                          W3, b3, W4, b4, out, n_total);
}